// Round 9
// baseline (248.763 us; speedup 1.0000x reference)
//
#include <hip/hip_runtime.h>

#define NROWS 8192
#define HALF_N 4096
#define DIM 512
#define INV_T 10.0f
#define NRB 64              // number of 128-row blocks
#define NBLOCKS 2080        // 64*65/2 upper-triangle block pairs

typedef __attribute__((ext_vector_type(4))) float f32x4;
typedef __attribute__((ext_vector_type(4))) int i32x4;
typedef __attribute__((ext_vector_type(8))) int i32x8;

// async 16B global -> LDS (DMA). LDS dest is wave-uniform base + lane*16.
__device__ __forceinline__ void async16(const void* g, void* l) {
  __builtin_amdgcn_global_load_lds(
      (const __attribute__((address_space(1))) unsigned int*)g,
      (__attribute__((address_space(3))) unsigned int*)l, 16, 0, 0);
}

// Kernel 1: L2-normalize rows of [f1;f2] -> fp8 e4m3 Fn (natural k order);
// zero rowsum. 256 threads = 4 waves, one row per wave.
__global__ __launch_bounds__(256) void norm_cast_k(
    const float* __restrict__ f1, const float* __restrict__ f2,
    unsigned char* __restrict__ Fn, float* __restrict__ rowsum) {
  int wave = threadIdx.x >> 6;
  int lane = threadIdx.x & 63;
  int row = blockIdx.x * 4 + wave;
  const float* src = (row < HALF_N) ? (f1 + (size_t)row * DIM)
                                    : (f2 + (size_t)(row - HALF_N) * DIM);
  const float4* p = reinterpret_cast<const float4*>(src + lane * 8);
  float4 v0 = p[0];
  float4 v1 = p[1];
  float ss = v0.x*v0.x + v0.y*v0.y + v0.z*v0.z + v0.w*v0.w
           + v1.x*v1.x + v1.y*v1.y + v1.z*v1.z + v1.w*v1.w;
  #pragma unroll
  for (int off = 1; off < 64; off <<= 1) ss += __shfl_xor(ss, off);
  float scale = 1.0f / fmaxf(sqrtf(ss), 1e-12f);
  int lo = __builtin_amdgcn_cvt_pk_fp8_f32(v0.x * scale, v0.y * scale, 0, false);
  lo = __builtin_amdgcn_cvt_pk_fp8_f32(v0.z * scale, v0.w * scale, lo, true);
  int hi = __builtin_amdgcn_cvt_pk_fp8_f32(v1.x * scale, v1.y * scale, 0, false);
  hi = __builtin_amdgcn_cvt_pk_fp8_f32(v1.z * scale, v1.w * scale, hi, true);
  *reinterpret_cast<int2*>(Fn + (size_t)row * DIM + lane * 8) = make_int2(lo, hi);
  if (lane == 0) rowsum[row] = 0.0f;
}

// Kernel 2: symmetric upper-triangle sim GEMM using MX-scaled fp8 MFMA
// (scale = 1.0): v_mfma_scale_f32_16x16x128_f8f6f4, 2x the non-scaled fp8
// rate. 128x128 tiles, BK=128 (4 rounds), staging via global_load_lds
// (32 x 1KB insts/round), 4 waves x (64x64) register tiles.
// LDS rows are 128 B (8 x 16B chunks); physical chunk = logical ^ (row&7):
// rows are bank-aligned so banks depend only on chunk, and every 16-lane
// group covers all 8 chunks exactly twice -> conflict-free b128 reads.
__global__ __launch_bounds__(256, 3) void sym_gemm_k(
    const unsigned char* __restrict__ Fn, float* __restrict__ rowsum,
    float* __restrict__ pairsim) {
  // XCD-contiguous remap: each XCD (bx%8) gets a contiguous 260-block range
  int bx = blockIdx.x;
  int gbx = (bx & 7) * (NBLOCKS / 8) + (bx >> 3);
  int rb = 0, rem = gbx;
  while (rem >= NRB - rb) { rem -= NRB - rb; ++rb; }
  const int cb = rb + rem;
  const int row0 = rb * 128, col0 = cb * 128;

  const int tid = threadIdx.x;
  const int wave = tid >> 6;
  const int lane = tid & 63;
  const int quad = lane >> 4;
  const int colid = lane & 15;
  const int wr0 = (wave >> 1) * 64;   // wave's row offset within tile
  const int wc0 = (wave & 1) * 64;    // wave's col offset within tile

  __shared__ __align__(16) unsigned char Alds[128 * 128];  // 16 KB
  __shared__ __align__(16) unsigned char Blds[128 * 128];  // 16 KB
  __shared__ float redrow[128];
  __shared__ float redcol[128];

  if (tid < 128) { redrow[tid] = 0.0f; redcol[tid] = 0.0f; }

  // Staging: 32 x 1KB insts/round (16 A + 16 B); wave w owns A insts
  // {w+4s} and B insts {w+4s}, s=0..3. Inst i covers rows [i*8, i*8+8).
  // lane -> local row r = i*8 + (lane>>3), phys chunk = lane&7; global
  // logical chunk = (lane&7) ^ (lane>>3)   (r&7 == lane>>3).
  const unsigned char* srcA[4]; const unsigned char* srcB[4];
  unsigned char* dstA[4]; unsigned char* dstB[4];
  #pragma unroll
  for (int seg = 0; seg < 4; ++seg) {
    int inst = wave + seg * 4;
    int r = inst * 8 + (lane >> 3);
    int c = (lane & 7) ^ (lane >> 3);
    srcA[seg] = Fn + (size_t)(row0 + r) * DIM + c * 16;
    srcB[seg] = Fn + (size_t)(col0 + r) * DIM + c * 16;
    dstA[seg] = Alds + inst * 1024;   // 8 rows x 128 B per inst
    dstB[seg] = Blds + inst * 1024;
  }

  // Fragment LDS pointers. 16x16x128 f8f6f4 A operand: lane holds
  // A[m = colid][k = quad*32 + j], j=0..31 -> logical chunks {2q, 2q+1};
  // physical = logical ^ (row&7). Two ds_read_b128 per fragment.
  const unsigned char* afp0[4]; const unsigned char* afp1[4];
  const unsigned char* bfp0[4]; const unsigned char* bfp1[4];
  #pragma unroll
  for (int t = 0; t < 4; ++t) {
    int ra = wr0 + t * 16 + colid;
    int rc = wc0 + t * 16 + colid;
    int ca0 = (2 * quad) ^ (ra & 7);
    int cb0 = (2 * quad) ^ (rc & 7);
    afp0[t] = Alds + ra * 128 + ca0 * 16;
    afp1[t] = Alds + ra * 128 + (ca0 ^ 1) * 16;
    bfp0[t] = Blds + rc * 128 + cb0 * 16;
    bfp1[t] = Blds + rc * 128 + (cb0 ^ 1) * 16;
  }

  f32x4 acc[4][4];
  #pragma unroll
  for (int t = 0; t < 4; ++t)
    #pragma unroll
    for (int u = 0; u < 4; ++u) acc[t][u] = (f32x4){0.f, 0.f, 0.f, 0.f};

  for (int kc = 0; kc < 4; ++kc) {
    __syncthreads();                    // prior round's reads done
    const size_t ko = (size_t)kc * 128; // 128 k-elems = 128 B per row
    #pragma unroll
    for (int seg = 0; seg < 4; ++seg) {
      async16(srcA[seg] + ko, dstA[seg]);
      async16(srcB[seg] + ko, dstB[seg]);
    }
    __syncthreads();                    // drains DMA -> tiles visible

    i32x8 af[4], bf[4];
    #pragma unroll
    for (int t = 0; t < 4; ++t) {
      i32x4 lo = *reinterpret_cast<const i32x4*>(afp0[t]);
      i32x4 hi = *reinterpret_cast<const i32x4*>(afp1[t]);
      af[t] = (i32x8){lo.x, lo.y, lo.z, lo.w, hi.x, hi.y, hi.z, hi.w};
    }
    #pragma unroll
    for (int u = 0; u < 4; ++u) {
      i32x4 lo = *reinterpret_cast<const i32x4*>(bfp0[u]);
      i32x4 hi = *reinterpret_cast<const i32x4*>(bfp1[u]);
      bf[u] = (i32x8){lo.x, lo.y, lo.z, lo.w, hi.x, hi.y, hi.z, hi.w};
    }
    #pragma unroll
    for (int t = 0; t < 4; ++t)
      #pragma unroll
      for (int u = 0; u < 4; ++u)
        acc[t][u] = __builtin_amdgcn_mfma_scale_f32_16x16x128_f8f6f4(
            af[t], bf[u], acc[t][u],
            0 /*cbsz: A=fp8 e4m3*/, 0 /*blgp: B=fp8 e4m3*/,
            0, 127 /*scale A = 2^0*/, 0, 127 /*scale B = 2^0*/);
  }

  // Epilogue. C/D layout: col = lane&15, row = quad*4 + reg (shape-
  // determined on gfx950, m127/m128-verified for the scaled 16x16 family).
  float re[4][4];
  float ce[4];
  #pragma unroll
  for (int t = 0; t < 4; ++t)
    #pragma unroll
    for (int r = 0; r < 4; ++r) re[t][r] = 0.0f;
  #pragma unroll
  for (int u = 0; u < 4; ++u) ce[u] = 0.0f;

  #pragma unroll
  for (int t = 0; t < 4; ++t) {
    #pragma unroll
    for (int u = 0; u < 4; ++u) {
      f32x4 a = acc[t][u];
      const int gc = col0 + wc0 + u * 16 + colid;
      #pragma unroll
      for (int r = 0; r < 4; ++r) {
        int grow = row0 + wr0 + t * 16 + quad * 4 + r;
        float sim = a[r] * INV_T;
        float e = (gc > grow) ? __expf(sim) : 0.0f;  // strict upper triangle
        re[t][r] += e;
        ce[u] += e;
        if (gc == grow + HALF_N && grow < HALF_N) {
          pairsim[grow] = sim;          // unique writer per pair
          pairsim[gc] = sim;
        }
      }
    }
  }

  // Row sums: reduce across the 16 col-lanes, LDS-accumulate.
  #pragma unroll
  for (int t = 0; t < 4; ++t)
    #pragma unroll
    for (int r = 0; r < 4; ++r) {
      float v = re[t][r];
      v += __shfl_xor(v, 1); v += __shfl_xor(v, 2);
      v += __shfl_xor(v, 4); v += __shfl_xor(v, 8);
      if (colid == 0) atomicAdd(&redrow[wr0 + t * 16 + quad * 4 + r], v);
    }
  // Col sums: reduce across the 4 quads (this wave's 64 rows).
  #pragma unroll
  for (int u = 0; u < 4; ++u) {
    float v = ce[u];
    v += __shfl_xor(v, 16); v += __shfl_xor(v, 32);
    if (lane < 16) atomicAdd(&redcol[wc0 + u * 16 + colid], v);
  }
  __syncthreads();
  if (tid < 128) atomicAdd(&rowsum[row0 + tid], redrow[tid]);
  else           atomicAdd(&rowsum[col0 + tid - 128], redcol[tid - 128]);
}

// Kernel 3: loss = mean_i( log(rowsum_i) - pairsim_i ). Single block.
__global__ __launch_bounds__(1024) void finalize_k(
    const float* __restrict__ rowsum, const float* __restrict__ pairsim,
    float* __restrict__ out) {
  float local = 0.0f;
  for (int i = threadIdx.x; i < NROWS; i += 1024)
    local += logf(rowsum[i]) - pairsim[i];
  #pragma unroll
  for (int off = 1; off < 64; off <<= 1) local += __shfl_xor(local, off);
  __shared__ float red[16];
  int wave = threadIdx.x >> 6;
  int lane = threadIdx.x & 63;
  if (lane == 0) red[wave] = local;
  __syncthreads();
  if (threadIdx.x == 0) {
    float s = 0.0f;
    #pragma unroll
    for (int w = 0; w < 16; ++w) s += red[w];
    out[0] = s * (1.0f / (float)NROWS);
  }
}

extern "C" void kernel_launch(void* const* d_in, const int* in_sizes, int n_in,
                              void* d_out, int out_size, void* d_ws, size_t ws_size,
                              hipStream_t stream) {
  const float* f1 = (const float*)d_in[0];
  const float* f2 = (const float*)d_in[1];
  unsigned char* Fn = (unsigned char*)d_ws;                     // 4 MB fp8
  float* rowsum = (float*)((char*)d_ws + (size_t)NROWS * DIM);
  float* pairsim = rowsum + NROWS;
  float* out = (float*)d_out;

  norm_cast_k<<<NROWS / 4, 256, 0, stream>>>(f1, f2, Fn, rowsum);
  sym_gemm_k<<<NBLOCKS, 256, 0, stream>>>(Fn, rowsum, pairsim);
  finalize_k<<<1, 1024, 0, stream>>>(rowsum, pairsim, out);
}

// Round 10
// 235.118 us; speedup vs baseline: 1.0580x; 1.0580x over previous
//
#include <hip/hip_runtime.h>

#define NROWS 8192
#define HALF_N 4096
#define DIM 512
#define INV_T 10.0f
#define NRB 64              // number of 128-row blocks
#define NBLOCKS 2080        // 64*65/2 upper-triangle block pairs

typedef __attribute__((ext_vector_type(4))) float f32x4;
typedef __attribute__((ext_vector_type(16))) float f32x16;
typedef __attribute__((ext_vector_type(4))) int i32x4;
typedef __attribute__((ext_vector_type(8))) int i32x8;

// async 16B global -> LDS (DMA). LDS dest is wave-uniform base + lane*16.
__device__ __forceinline__ void async16(const void* g, void* l) {
  __builtin_amdgcn_global_load_lds(
      (const __attribute__((address_space(1))) unsigned int*)g,
      (__attribute__((address_space(3))) unsigned int*)l, 16, 0, 0);
}

// Kernel 1: L2-normalize rows of [f1;f2] -> fp8 e4m3 Fn (natural k order);
// zero rowsum. 256 threads = 4 waves, one row per wave.
__global__ __launch_bounds__(256) void norm_cast_k(
    const float* __restrict__ f1, const float* __restrict__ f2,
    unsigned char* __restrict__ Fn, float* __restrict__ rowsum) {
  int wave = threadIdx.x >> 6;
  int lane = threadIdx.x & 63;
  int row = blockIdx.x * 4 + wave;
  const float* src = (row < HALF_N) ? (f1 + (size_t)row * DIM)
                                    : (f2 + (size_t)(row - HALF_N) * DIM);
  const float4* p = reinterpret_cast<const float4*>(src + lane * 8);
  float4 v0 = p[0];
  float4 v1 = p[1];
  float ss = v0.x*v0.x + v0.y*v0.y + v0.z*v0.z + v0.w*v0.w
           + v1.x*v1.x + v1.y*v1.y + v1.z*v1.z + v1.w*v1.w;
  #pragma unroll
  for (int off = 1; off < 64; off <<= 1) ss += __shfl_xor(ss, off);
  float scale = 1.0f / fmaxf(sqrtf(ss), 1e-12f);
  int lo = __builtin_amdgcn_cvt_pk_fp8_f32(v0.x * scale, v0.y * scale, 0, false);
  lo = __builtin_amdgcn_cvt_pk_fp8_f32(v0.z * scale, v0.w * scale, lo, true);
  int hi = __builtin_amdgcn_cvt_pk_fp8_f32(v1.x * scale, v1.y * scale, 0, false);
  hi = __builtin_amdgcn_cvt_pk_fp8_f32(v1.z * scale, v1.w * scale, hi, true);
  *reinterpret_cast<int2*>(Fn + (size_t)row * DIM + lane * 8) = make_int2(lo, hi);
  if (lane == 0) rowsum[row] = 0.0f;
}

// Kernel 2: symmetric upper-triangle sim GEMM using MX-scaled fp8 MFMA at
// 32x32x64 (scale = 1.0, 2x the non-scaled fp8 rate), fused exp row/col
// accumulation. 128x128 tiles, BK=64 (8 rounds) with the R7-proven staging
// (16 x 1KB global_load_lds insts/round, 4-chunk ^((r>>1)&3) swizzle).
// Each wave: 2x2 tiles of 32x32 (64x64 register tile) -> af[2]+bf[2] live
// (32 VGPRs), acc 4 x f32x16 (AGPR) -> no spill (the R9 failure mode).
__global__ __launch_bounds__(256, 3) void sym_gemm_k(
    const unsigned char* __restrict__ Fn, float* __restrict__ rowsum,
    float* __restrict__ pairsim) {
  // XCD-contiguous remap: each XCD (bx%8) gets a contiguous 260-block range
  int bx = blockIdx.x;
  int gbx = (bx & 7) * (NBLOCKS / 8) + (bx >> 3);
  int rb = 0, rem = gbx;
  while (rem >= NRB - rb) { rem -= NRB - rb; ++rb; }
  const int cb = rb + rem;
  const int row0 = rb * 128, col0 = cb * 128;

  const int tid = threadIdx.x;
  const int wave = tid >> 6;
  const int lane = tid & 63;
  const int l31 = lane & 31;
  const int half = lane >> 5;          // k-half selector for A/B fragments
  const int wr0 = (wave >> 1) * 64;    // wave's row offset within tile
  const int wc0 = (wave & 1) * 64;     // wave's col offset within tile

  // LDS tiles: 128 rows x 64 k fp8 = 64 B/row, 4 x 16B chunks per row.
  // Physical chunk = logical ^ ((row>>1)&3).
  __shared__ __align__(16) unsigned char Alds[128 * 64];
  __shared__ __align__(16) unsigned char Blds[128 * 64];
  __shared__ float redrow[128];
  __shared__ float redcol[128];

  if (tid < 128) { redrow[tid] = 0.0f; redcol[tid] = 0.0f; }

  // Staging (R7-proven): 16 x 1KB insts/round (8 A + 8 B), wave w owns
  // A insts {w, w+4}, B insts {w, w+4}. Inst i covers rows [i*16, i*16+16):
  // lane -> r = i*16 + (lane>>2), phys chunk = lane&3,
  // global logical chunk = (lane&3) ^ ((r>>1)&3).
  const unsigned char* srcA[2]; const unsigned char* srcB[2];
  unsigned char* dstA[2]; unsigned char* dstB[2];
  #pragma unroll
  for (int seg = 0; seg < 2; ++seg) {
    int inst = wave + seg * 4;
    int r = inst * 16 + (lane >> 2);
    int c = (lane & 3) ^ ((r >> 1) & 3);
    srcA[seg] = Fn + (size_t)(row0 + r) * DIM + c * 16;
    srcB[seg] = Fn + (size_t)(col0 + r) * DIM + c * 16;
    dstA[seg] = Alds + inst * 1024;   // 16 rows x 64 B per inst
    dstB[seg] = Blds + inst * 1024;
  }

  // Fragment LDS pointers. 32x32x64 f8f6f4 A operand: lane holds
  // A[m = lane&31][k = half*32 + j], j=0..31 -> logical chunks {2*half,
  // 2*half+1}; physical = logical ^ ((row>>1)&3). afp1 = afp0 with chunk
  // bit0 flipped (bit 4 of the byte offset).
  const unsigned char* afp0[2]; const unsigned char* bfp0[2];
  #pragma unroll
  for (int t = 0; t < 2; ++t) {
    int ra = wr0 + t * 32 + l31;
    int rc = wc0 + t * 32 + l31;
    afp0[t] = Alds + ra * 64 + (((2 * half) ^ ((ra >> 1) & 3)) << 4);
    bfp0[t] = Blds + rc * 64 + (((2 * half) ^ ((rc >> 1) & 3)) << 4);
  }

  f32x16 acc[2][2];
  #pragma unroll
  for (int t = 0; t < 2; ++t)
    #pragma unroll
    for (int u = 0; u < 2; ++u)
      #pragma unroll
      for (int r = 0; r < 16; ++r) acc[t][u][r] = 0.0f;

  for (int kc = 0; kc < 8; ++kc) {
    __syncthreads();                   // prior round's reads done
    const size_t ko = (size_t)kc * 64; // 64 k-elems = 64 B per row
    #pragma unroll
    for (int seg = 0; seg < 2; ++seg) {
      async16(srcA[seg] + ko, dstA[seg]);
      async16(srcB[seg] + ko, dstB[seg]);
    }
    __syncthreads();                   // drains DMA -> tiles visible

    union frag { struct { i32x4 lo, hi; } p; i32x8 v; };
    frag af[2], bf[2];
    #pragma unroll
    for (int t = 0; t < 2; ++t) {
      af[t].p.lo = *reinterpret_cast<const i32x4*>(afp0[t]);
      af[t].p.hi = *reinterpret_cast<const i32x4*>(
          (const unsigned char*)((size_t)afp0[t] ^ 16));
      bf[t].p.lo = *reinterpret_cast<const i32x4*>(bfp0[t]);
      bf[t].p.hi = *reinterpret_cast<const i32x4*>(
          (const unsigned char*)((size_t)bfp0[t] ^ 16));
    }
    #pragma unroll
    for (int t = 0; t < 2; ++t)
      #pragma unroll
      for (int u = 0; u < 2; ++u)
        acc[t][u] = __builtin_amdgcn_mfma_scale_f32_32x32x64_f8f6f4(
            af[t].v, bf[u].v, acc[t][u],
            0 /*cbsz: A=fp8 e4m3*/, 0 /*blgp: B=fp8 e4m3*/,
            0, 127 /*scale A = 2^0*/, 0, 127 /*scale B = 2^0*/);
  }

  // Epilogue. 32x32 C/D layout (m74/m101-verified, shape-determined):
  // col = lane&31, row = (reg&3) + 8*(reg>>2) + 4*(lane>>5).
  float re[2][16];                     // per (t, reg) row contribution
  float ce[2];                         // per u col contribution
  #pragma unroll
  for (int t = 0; t < 2; ++t)
    #pragma unroll
    for (int r = 0; r < 16; ++r) re[t][r] = 0.0f;
  ce[0] = 0.0f; ce[1] = 0.0f;

  #pragma unroll
  for (int t = 0; t < 2; ++t) {
    #pragma unroll
    for (int u = 0; u < 2; ++u) {
      const int gc = col0 + wc0 + u * 32 + l31;
      #pragma unroll
      for (int r = 0; r < 16; ++r) {
        int grow = row0 + wr0 + t * 32 + (r & 3) + 8 * (r >> 2) + 4 * half;
        float sim = acc[t][u][r] * INV_T;
        float e = (gc > grow) ? __expf(sim) : 0.0f;  // strict upper triangle
        re[t][r] += e;
        ce[u] += e;
        if (gc == grow + HALF_N && grow < HALF_N) {
          pairsim[grow] = sim;         // unique writer per pair
          pairsim[gc] = sim;
        }
      }
    }
  }

  // Row sums: each row held by the 32 lanes sharing `half`; reduce over l31.
  #pragma unroll
  for (int t = 0; t < 2; ++t)
    #pragma unroll
    for (int r = 0; r < 16; ++r) {
      float v = re[t][r];
      v += __shfl_xor(v, 1); v += __shfl_xor(v, 2);
      v += __shfl_xor(v, 4); v += __shfl_xor(v, 8);
      v += __shfl_xor(v, 16);
      if (l31 == 0)                    // lanes 0 and 32 -> different rows
        atomicAdd(&redrow[wr0 + t * 32 + (r & 3) + 8 * (r >> 2) + 4 * half], v);
    }
  // Col sums: column = l31 (per u); reduce over the two halves.
  #pragma unroll
  for (int u = 0; u < 2; ++u) {
    float v = ce[u];
    v += __shfl_xor(v, 32);
    if (half == 0) atomicAdd(&redcol[wc0 + u * 32 + l31], v);
  }
  __syncthreads();
  if (tid < 128) atomicAdd(&rowsum[row0 + tid], redrow[tid]);
  else           atomicAdd(&rowsum[col0 + tid - 128], redcol[tid - 128]);
}

// Kernel 3: loss = mean_i( log(rowsum_i) - pairsim_i ). Single block.
__global__ __launch_bounds__(1024) void finalize_k(
    const float* __restrict__ rowsum, const float* __restrict__ pairsim,
    float* __restrict__ out) {
  float local = 0.0f;
  for (int i = threadIdx.x; i < NROWS; i += 1024)
    local += logf(rowsum[i]) - pairsim[i];
  #pragma unroll
  for (int off = 1; off < 64; off <<= 1) local += __shfl_xor(local, off);
  __shared__ float red[16];
  int wave = threadIdx.x >> 6;
  int lane = threadIdx.x & 63;
  if (lane == 0) red[wave] = local;
  __syncthreads();
  if (threadIdx.x == 0) {
    float s = 0.0f;
    #pragma unroll
    for (int w = 0; w < 16; ++w) s += red[w];
    out[0] = s * (1.0f / (float)NROWS);
  }
}

extern "C" void kernel_launch(void* const* d_in, const int* in_sizes, int n_in,
                              void* d_out, int out_size, void* d_ws, size_t ws_size,
                              hipStream_t stream) {
  const float* f1 = (const float*)d_in[0];
  const float* f2 = (const float*)d_in[1];
  unsigned char* Fn = (unsigned char*)d_ws;                     // 4 MB fp8
  float* rowsum = (float*)((char*)d_ws + (size_t)NROWS * DIM);
  float* pairsim = rowsum + NROWS;
  float* out = (float*)d_out;

  norm_cast_k<<<NROWS / 4, 256, 0, stream>>>(f1, f2, Fn, rowsum);
  sym_gemm_k<<<NBLOCKS, 256, 0, stream>>>(Fn, rowsum, pairsim);
  finalize_k<<<1, 1024, 0, stream>>>(rowsum, pairsim, out);
}

// Round 11
// 108.144 us; speedup vs baseline: 2.3003x; 2.1741x over previous
//
#include <hip/hip_runtime.h>

#define NROWS 8192
#define HALF_N 4096
#define DIM 512
#define INV_T 10.0f
#define NRB 64              // number of 128-row blocks
#define NBLOCKS 2080        // 64*65/2 upper-triangle block pairs

typedef __attribute__((ext_vector_type(4))) float f32x4;
typedef __attribute__((ext_vector_type(2))) long long2v;

// async 16B global -> LDS (DMA). LDS dest is wave-uniform base + lane*16.
__device__ __forceinline__ void async16(const void* g, void* l) {
  __builtin_amdgcn_global_load_lds(
      (const __attribute__((address_space(1))) unsigned int*)g,
      (__attribute__((address_space(3))) unsigned int*)l, 16, 0, 0);
}

// Kernel 1: L2-normalize rows of [f1;f2] -> fp8 e4m3 Fn; zero rowsum and out.
// K-PERMUTED layout (R8-proven): within each 64-byte k-group, 8B unit u is
// stored at position p = 2*(u&3) + (u>>2), so each lane's two K=32 fragments
// are adjacent -> single ds_read_b128 per fragment pair in the GEMM.
__global__ __launch_bounds__(256) void norm_cast_k(
    const float* __restrict__ f1, const float* __restrict__ f2,
    unsigned char* __restrict__ Fn, float* __restrict__ rowsum,
    float* __restrict__ out) {
  int wave = threadIdx.x >> 6;
  int lane = threadIdx.x & 63;
  int row = blockIdx.x * 4 + wave;
  const float* src = (row < HALF_N) ? (f1 + (size_t)row * DIM)
                                    : (f2 + (size_t)(row - HALF_N) * DIM);
  const float4* p = reinterpret_cast<const float4*>(src + lane * 8);
  float4 v0 = p[0];
  float4 v1 = p[1];
  float ss = v0.x*v0.x + v0.y*v0.y + v0.z*v0.z + v0.w*v0.w
           + v1.x*v1.x + v1.y*v1.y + v1.z*v1.z + v1.w*v1.w;
  #pragma unroll
  for (int off = 1; off < 64; off <<= 1) ss += __shfl_xor(ss, off);
  float scale = 1.0f / fmaxf(sqrtf(ss), 1e-12f);
  int lo = __builtin_amdgcn_cvt_pk_fp8_f32(v0.x * scale, v0.y * scale, 0, false);
  lo = __builtin_amdgcn_cvt_pk_fp8_f32(v0.z * scale, v0.w * scale, lo, true);
  int hi = __builtin_amdgcn_cvt_pk_fp8_f32(v1.x * scale, v1.y * scale, 0, false);
  hi = __builtin_amdgcn_cvt_pk_fp8_f32(v1.z * scale, v1.w * scale, hi, true);
  int u = lane & 7;
  int g = lane >> 3;
  int pos = 2 * (u & 3) + (u >> 2);          // permuted unit position
  *reinterpret_cast<int2*>(Fn + (size_t)row * DIM + g * 64 + pos * 8) =
      make_int2(lo, hi);
  if (lane == 0) rowsum[row] = 0.0f;
  if (blockIdx.x == 0 && threadIdx.x == 0) out[0] = 0.0f;
}

// Kernel 2: symmetric upper-triangle sim GEMM (fp8 e4m3, k-permuted), fused
// exp row+col accumulation. 128x128 tiles, BK=128 (4 rounds, 8 barriers),
// staging via global_load_lds (32 x 1KB insts/round), 4 waves x (64x64)
// register tiles. LDS rows are 128 B (8 x 16B chunks); physical chunk =
// logical ^ (row&7): banks depend only on chunk, each 16-lane read phase
// covers all 8 chunks exactly twice -> <=2-way (free). The round's K=128 is
// consumed in two K=64 g-phases (8 b128 frag loads + 32 MFMAs each) so live
// register state matches the proven R8 shape (no spill).
__global__ __launch_bounds__(256, 3) void sym_gemm_k(
    const unsigned char* __restrict__ Fn, float* __restrict__ rowsum,
    float* __restrict__ pairsim) {
  // XCD-contiguous remap: each XCD (bx%8) gets a contiguous 260-block range
  int bx = blockIdx.x;
  int gbx = (bx & 7) * (NBLOCKS / 8) + (bx >> 3);
  int rb = 0, rem = gbx;
  while (rem >= NRB - rb) { rem -= NRB - rb; ++rb; }
  const int cb = rb + rem;
  const int row0 = rb * 128, col0 = cb * 128;

  const int tid = threadIdx.x;
  const int wave = tid >> 6;
  const int lane = tid & 63;
  const int quad = lane >> 4;
  const int colid = lane & 15;
  const int wr0 = (wave >> 1) * 64;   // wave's row offset within tile
  const int wc0 = (wave & 1) * 64;    // wave's col offset within tile

  __shared__ __align__(128) unsigned char Alds[128 * 128];  // 16 KB
  __shared__ __align__(128) unsigned char Blds[128 * 128];  // 16 KB
  __shared__ float redrow[128];
  __shared__ float redcol[128];

  if (tid < 128) { redrow[tid] = 0.0f; redcol[tid] = 0.0f; }

  // Staging: 32 x 1KB insts/round (16 A + 16 B); wave w owns A insts
  // {w+4s} and B insts {w+4s}, s=0..3. Inst i covers rows [i*8, i*8+8):
  // lane -> local row r = i*8 + (lane>>3), phys chunk = lane&7; global
  // logical chunk = (lane&7) ^ (lane>>3)   (r&7 == lane>>3).
  const unsigned char* srcA[4]; const unsigned char* srcB[4];
  unsigned char* dstA[4]; unsigned char* dstB[4];
  #pragma unroll
  for (int seg = 0; seg < 4; ++seg) {
    int inst = wave + seg * 4;
    int r = inst * 8 + (lane >> 3);
    int c = (lane & 7) ^ (lane >> 3);
    srcA[seg] = Fn + (size_t)(row0 + r) * DIM + c * 16;
    srcB[seg] = Fn + (size_t)(col0 + r) * DIM + c * 16;
    dstA[seg] = Alds + inst * 1024;   // 8 rows x 128 B per inst
    dstB[seg] = Blds + inst * 1024;
  }

  // Fragment LDS pointers (g=0 base). Logical chunk for k-group g, quad q
  // is g*4 + q (k-permuted pairs); physical = logical ^ (row&7). The g=1
  // address is base with chunk bit2 flipped = byte offset ^ 64 (arrays are
  // 128-aligned so the absolute-address XOR is valid).
  const unsigned char* afp[4]; const unsigned char* bfp[4];
  #pragma unroll
  for (int t = 0; t < 4; ++t) {
    int ra = wr0 + t * 16 + colid;
    int rc = wc0 + t * 16 + colid;
    afp[t] = Alds + ra * 128 + ((quad ^ (ra & 7)) << 4);
    bfp[t] = Blds + rc * 128 + ((quad ^ (rc & 7)) << 4);
  }

  f32x4 acc[4][4];
  #pragma unroll
  for (int t = 0; t < 4; ++t)
    #pragma unroll
    for (int u = 0; u < 4; ++u) acc[t][u] = (f32x4){0.f, 0.f, 0.f, 0.f};

  for (int kc = 0; kc < 4; ++kc) {
    __syncthreads();                    // prior round's reads done
    const size_t ko = (size_t)kc * 128; // 128 k-elems = 128 B per row
    #pragma unroll
    for (int seg = 0; seg < 4; ++seg) {
      async16(srcA[seg] + ko, dstA[seg]);
      async16(srcB[seg] + ko, dstB[seg]);
    }
    __syncthreads();                    // drains DMA -> tiles visible

    #pragma unroll
    for (int g = 0; g < 2; ++g) {
      long2v af[4], bf[4];
      #pragma unroll
      for (int t = 0; t < 4; ++t)
        af[t] = *reinterpret_cast<const long2v*>(
            (const unsigned char*)((uintptr_t)afp[t] ^ (g ? 64u : 0u)));
      #pragma unroll
      for (int u = 0; u < 4; ++u)
        bf[u] = *reinterpret_cast<const long2v*>(
            (const unsigned char*)((uintptr_t)bfp[u] ^ (g ? 64u : 0u)));
      #pragma unroll
      for (int s = 0; s < 2; ++s)
        #pragma unroll
        for (int t = 0; t < 4; ++t)
          #pragma unroll
          for (int u = 0; u < 4; ++u)
            acc[t][u] = __builtin_amdgcn_mfma_f32_16x16x32_fp8_fp8(
                af[t][s], bf[u][s], acc[t][u], 0, 0, 0);
    }
  }

  // Epilogue. C/D layout: col = lane&15, row = quad*4 + reg (m89-verified,
  // dtype-independent on gfx950).
  float re[4][4];
  float ce[4];
  #pragma unroll
  for (int t = 0; t < 4; ++t)
    #pragma unroll
    for (int r = 0; r < 4; ++r) re[t][r] = 0.0f;
  #pragma unroll
  for (int u = 0; u < 4; ++u) ce[u] = 0.0f;

  #pragma unroll
  for (int t = 0; t < 4; ++t) {
    #pragma unroll
    for (int u = 0; u < 4; ++u) {
      f32x4 a = acc[t][u];
      const int gc = col0 + wc0 + u * 16 + colid;
      #pragma unroll
      for (int r = 0; r < 4; ++r) {
        int grow = row0 + wr0 + t * 16 + quad * 4 + r;
        float sim = a[r] * INV_T;
        float e = (gc > grow) ? __expf(sim) : 0.0f;  // strict upper triangle
        re[t][r] += e;
        ce[u] += e;
        if (gc == grow + HALF_N && grow < HALF_N) {
          pairsim[grow] = sim;         // unique writer per pair
          pairsim[gc] = sim;
        }
      }
    }
  }

  // Row sums: reduce across the 16 col-lanes, LDS-accumulate.
  #pragma unroll
  for (int t = 0; t < 4; ++t)
    #pragma unroll
    for (int r = 0; r < 4; ++r) {
      float v = re[t][r];
      v += __shfl_xor(v, 1); v += __shfl_xor(v, 2);
      v += __shfl_xor(v, 4); v += __shfl_xor(v, 8);
      if (colid == 0) atomicAdd(&redrow[wr0 + t * 16 + quad * 4 + r], v);
    }
  // Col sums: reduce across the 4 quads (this wave's 64 rows).
  #pragma unroll
  for (int u = 0; u < 4; ++u) {
    float v = ce[u];
    v += __shfl_xor(v, 16); v += __shfl_xor(v, 32);
    if (lane < 16) atomicAdd(&redcol[wc0 + u * 16 + colid], v);
  }
  __syncthreads();
  if (tid < 128) atomicAdd(&rowsum[row0 + tid], redrow[tid]);
  else           atomicAdd(&rowsum[col0 + tid - 128], redcol[tid - 128]);
}

// Kernel 3: loss partials. 32 blocks x 256 threads, one row each;
// per-wave reduce then one atomicAdd per wave into out (zeroed in kernel 1).
__global__ __launch_bounds__(256) void finalize_k(
    const float* __restrict__ rowsum, const float* __restrict__ pairsim,
    float* __restrict__ out) {
  int i = blockIdx.x * 256 + threadIdx.x;
  float local = logf(rowsum[i]) - pairsim[i];
  #pragma unroll
  for (int off = 1; off < 64; off <<= 1) local += __shfl_xor(local, off);
  if ((threadIdx.x & 63) == 0)
    atomicAdd(out, local * (1.0f / (float)NROWS));
}

extern "C" void kernel_launch(void* const* d_in, const int* in_sizes, int n_in,
                              void* d_out, int out_size, void* d_ws, size_t ws_size,
                              hipStream_t stream) {
  const float* f1 = (const float*)d_in[0];
  const float* f2 = (const float*)d_in[1];
  unsigned char* Fn = (unsigned char*)d_ws;                     // 4 MB fp8
  float* rowsum = (float*)((char*)d_ws + (size_t)NROWS * DIM);
  float* pairsim = rowsum + NROWS;
  float* out = (float*)d_out;

  norm_cast_k<<<NROWS / 4, 256, 0, stream>>>(f1, f2, Fn, rowsum, out);
  sym_gemm_k<<<NBLOCKS, 256, 0, stream>>>(Fn, rowsum, pairsim);
  finalize_k<<<NROWS / 256, 256, 0, stream>>>(rowsum, pairsim, out);
}

// Round 12
// 104.424 us; speedup vs baseline: 2.3822x; 1.0356x over previous
//
#include <hip/hip_runtime.h>

#define NROWS 8192
#define HALF_N 4096
#define DIM 512
#define INV_T 10.0f
#define NRB 64              // number of 128-row blocks
#define NBLOCKS 2080        // 64*65/2 upper-triangle block pairs

typedef __attribute__((ext_vector_type(4))) float f32x4;
typedef __attribute__((ext_vector_type(2))) long long2v;

// async 16B global -> LDS (DMA). LDS dest is wave-uniform base + lane*16.
__device__ __forceinline__ void async16(const void* g, void* l) {
  __builtin_amdgcn_global_load_lds(
      (const __attribute__((address_space(1))) unsigned int*)g,
      (__attribute__((address_space(3))) unsigned int*)l, 16, 0, 0);
}

// Kernel 1: L2-normalize rows of [f1;f2] -> fp8 e4m3 Fn; zero rowsum + out.
// K-PERMUTED layout (R8-proven): within each 64-byte k-group, 8B unit u is
// stored at position p = 2*(u&3) + (u>>2), so each lane's two K=32 fragments
// are adjacent -> single ds_read_b128 per fragment in the GEMM.
__global__ __launch_bounds__(256) void norm_cast_k(
    const float* __restrict__ f1, const float* __restrict__ f2,
    unsigned char* __restrict__ Fn, float* __restrict__ rowsum,
    float* __restrict__ out) {
  int wave = threadIdx.x >> 6;
  int lane = threadIdx.x & 63;
  int row = blockIdx.x * 4 + wave;
  const float* src = (row < HALF_N) ? (f1 + (size_t)row * DIM)
                                    : (f2 + (size_t)(row - HALF_N) * DIM);
  const float4* p = reinterpret_cast<const float4*>(src + lane * 8);
  float4 v0 = p[0];
  float4 v1 = p[1];
  float ss = v0.x*v0.x + v0.y*v0.y + v0.z*v0.z + v0.w*v0.w
           + v1.x*v1.x + v1.y*v1.y + v1.z*v1.z + v1.w*v1.w;
  #pragma unroll
  for (int off = 1; off < 64; off <<= 1) ss += __shfl_xor(ss, off);
  float scale = 1.0f / fmaxf(sqrtf(ss), 1e-12f);
  int lo = __builtin_amdgcn_cvt_pk_fp8_f32(v0.x * scale, v0.y * scale, 0, false);
  lo = __builtin_amdgcn_cvt_pk_fp8_f32(v0.z * scale, v0.w * scale, lo, true);
  int hi = __builtin_amdgcn_cvt_pk_fp8_f32(v1.x * scale, v1.y * scale, 0, false);
  hi = __builtin_amdgcn_cvt_pk_fp8_f32(v1.z * scale, v1.w * scale, hi, true);
  int u = lane & 7;
  int g = lane >> 3;
  int pos = 2 * (u & 3) + (u >> 2);          // permuted unit position
  *reinterpret_cast<int2*>(Fn + (size_t)row * DIM + g * 64 + pos * 8) =
      make_int2(lo, hi);
  if (lane == 0) rowsum[row] = 0.0f;
  if (blockIdx.x == 0 && threadIdx.x == 0) out[0] = 0.0f;
}

// Kernel 2: symmetric upper-triangle sim GEMM (fp8 e4m3, k-permuted), fused
// exp row+col accumulation. EXACT R8 structure (BK=64, 8 rounds, 16 x 1KB
// global_load_lds insts/round, ^((r>>1)&3) chunk swizzle, b128 frag reads),
// with occupancy raised to 4 blocks/CU: 60 VGPR + 64 AGPR = 124 <= 128, LDS
// 17.4 KB x 4 = 70 KB. DS pipe is per-CU shared, so the extra block adds
// drain overlap without adding DS work.
__global__ __launch_bounds__(256, 4) void sym_gemm_k(
    const unsigned char* __restrict__ Fn, float* __restrict__ rowsum,
    float* __restrict__ pairsim) {
  // XCD-contiguous remap: each XCD (bx%8) gets a contiguous 260-block range
  int bx = blockIdx.x;
  int gbx = (bx & 7) * (NBLOCKS / 8) + (bx >> 3);
  int rb = 0, rem = gbx;
  while (rem >= NRB - rb) { rem -= NRB - rb; ++rb; }
  const int cb = rb + rem;
  const int row0 = rb * 128, col0 = cb * 128;

  const int tid = threadIdx.x;
  const int wave = tid >> 6;
  const int lane = tid & 63;
  const int quad = lane >> 4;
  const int colid = lane & 15;
  const int wr0 = (wave >> 1) * 64;   // wave's row offset within tile
  const int wc0 = (wave & 1) * 64;    // wave's col offset within tile

  // LDS tiles: 128 rows x 64 k fp8 = 64 B/row, 4 x 16B chunks per row.
  // Physical chunk = logical ^ ((row>>1)&3) -> conflict-free b128 reads.
  __shared__ __align__(16) unsigned char Alds[128 * 64];
  __shared__ __align__(16) unsigned char Blds[128 * 64];
  __shared__ float redrow[128];
  __shared__ float redcol[128];

  if (tid < 128) { redrow[tid] = 0.0f; redcol[tid] = 0.0f; }

  // Staging: 16 x 1KB wave-instructions per round (8 A + 8 B), wave w owns
  // A insts {w, w+4} and B insts {w, w+4}. Inst i covers rows [i*16, i*16+16).
  // lane -> local row r = i*16 + (lane>>2), physical chunk p = lane&3;
  // global source uses logical chunk c = p ^ ((r>>1)&3) (swizzle inverse).
  const unsigned char* srcA[2]; const unsigned char* srcB[2];
  unsigned char* dstA[2]; unsigned char* dstB[2];
  #pragma unroll
  for (int seg = 0; seg < 2; ++seg) {
    int inst = wave + seg * 4;
    int r = inst * 16 + (lane >> 2);
    int c = (lane & 3) ^ ((r >> 1) & 3);
    srcA[seg] = Fn + (size_t)(row0 + r) * DIM + c * 16;
    srcB[seg] = Fn + (size_t)(col0 + r) * DIM + c * 16;
    dstA[seg] = Alds + inst * 1024;   // 16 rows x 64 B per inst
    dstB[seg] = Blds + inst * 1024;
  }

  // Fragment LDS addresses (constant across rounds): ONE b128 per row-tile.
  // Logical chunk = quad (holds both K=32 halves for this quad, k-permuted);
  // physical = quad ^ ((row>>1)&3).
  const unsigned char* afp[4]; const unsigned char* bfp[4];
  #pragma unroll
  for (int t = 0; t < 4; ++t) {
    int ra = wr0 + t * 16 + colid;
    int rc = wc0 + t * 16 + colid;
    afp[t] = Alds + ra * 64 + ((quad ^ ((ra >> 1) & 3)) << 4);
    bfp[t] = Blds + rc * 64 + ((quad ^ ((rc >> 1) & 3)) << 4);
  }

  f32x4 acc[4][4];
  #pragma unroll
  for (int t = 0; t < 4; ++t)
    #pragma unroll
    for (int u = 0; u < 4; ++u) acc[t][u] = (f32x4){0.f, 0.f, 0.f, 0.f};

  for (int kc = 0; kc < 8; ++kc) {
    __syncthreads();                   // prior round's reads done
    const size_t ko = (size_t)kc * 64; // 64 k-elems = 64 B per row
    #pragma unroll
    for (int seg = 0; seg < 2; ++seg) {
      async16(srcA[seg] + ko, dstA[seg]);
      async16(srcB[seg] + ko, dstB[seg]);
    }
    __syncthreads();                   // drains DMA -> tiles visible

    long2v af[4], bf[4];
    #pragma unroll
    for (int t = 0; t < 4; ++t) af[t] = *reinterpret_cast<const long2v*>(afp[t]);
    #pragma unroll
    for (int u = 0; u < 4; ++u) bf[u] = *reinterpret_cast<const long2v*>(bfp[u]);
    #pragma unroll
    for (int s = 0; s < 2; ++s)
      #pragma unroll
      for (int t = 0; t < 4; ++t)
        #pragma unroll
        for (int u = 0; u < 4; ++u)
          acc[t][u] = __builtin_amdgcn_mfma_f32_16x16x32_fp8_fp8(
              af[t][s], bf[u][s], acc[t][u], 0, 0, 0);
  }

  // Epilogue. C/D layout: col = lane&15, row = quad*4 + reg (m89-verified,
  // dtype-independent on gfx950).
  float re[4][4];
  float ce[4];
  #pragma unroll
  for (int t = 0; t < 4; ++t)
    #pragma unroll
    for (int r = 0; r < 4; ++r) re[t][r] = 0.0f;
  #pragma unroll
  for (int u = 0; u < 4; ++u) ce[u] = 0.0f;

  #pragma unroll
  for (int t = 0; t < 4; ++t) {
    #pragma unroll
    for (int u = 0; u < 4; ++u) {
      f32x4 a = acc[t][u];
      const int gc = col0 + wc0 + u * 16 + colid;
      #pragma unroll
      for (int r = 0; r < 4; ++r) {
        int grow = row0 + wr0 + t * 16 + quad * 4 + r;
        float sim = a[r] * INV_T;
        float e = (gc > grow) ? __expf(sim) : 0.0f;  // strict upper triangle
        re[t][r] += e;
        ce[u] += e;
        if (gc == grow + HALF_N && grow < HALF_N) {
          pairsim[grow] = sim;         // unique writer per pair
          pairsim[gc] = sim;
        }
      }
    }
  }

  // Row sums: reduce across the 16 col-lanes, LDS-accumulate.
  #pragma unroll
  for (int t = 0; t < 4; ++t)
    #pragma unroll
    for (int r = 0; r < 4; ++r) {
      float v = re[t][r];
      v += __shfl_xor(v, 1); v += __shfl_xor(v, 2);
      v += __shfl_xor(v, 4); v += __shfl_xor(v, 8);
      if (colid == 0) atomicAdd(&redrow[wr0 + t * 16 + quad * 4 + r], v);
    }
  // Col sums: reduce across the 4 quads (this wave's 64 rows).
  #pragma unroll
  for (int u = 0; u < 4; ++u) {
    float v = ce[u];
    v += __shfl_xor(v, 16); v += __shfl_xor(v, 32);
    if (lane < 16) atomicAdd(&redcol[wc0 + u * 16 + colid], v);
  }
  __syncthreads();
  if (tid < 128) atomicAdd(&rowsum[row0 + tid], redrow[tid]);
  else           atomicAdd(&rowsum[col0 + tid - 128], redcol[tid - 128]);
}

// Kernel 3: loss partials. 32 blocks x 256 threads, one row each;
// per-wave reduce then one atomicAdd per wave into out (zeroed in kernel 1).
__global__ __launch_bounds__(256) void finalize_k(
    const float* __restrict__ rowsum, const float* __restrict__ pairsim,
    float* __restrict__ out) {
  int i = blockIdx.x * 256 + threadIdx.x;
  float local = logf(rowsum[i]) - pairsim[i];
  #pragma unroll
  for (int off = 1; off < 64; off <<= 1) local += __shfl_xor(local, off);
  if ((threadIdx.x & 63) == 0)
    atomicAdd(out, local * (1.0f / (float)NROWS));
}

extern "C" void kernel_launch(void* const* d_in, const int* in_sizes, int n_in,
                              void* d_out, int out_size, void* d_ws, size_t ws_size,
                              hipStream_t stream) {
  const float* f1 = (const float*)d_in[0];
  const float* f2 = (const float*)d_in[1];
  unsigned char* Fn = (unsigned char*)d_ws;                     // 4 MB fp8
  float* rowsum = (float*)((char*)d_ws + (size_t)NROWS * DIM);
  float* pairsim = rowsum + NROWS;
  float* out = (float*)d_out;

  norm_cast_k<<<NROWS / 4, 256, 0, stream>>>(f1, f2, Fn, rowsum, out);
  sym_gemm_k<<<NBLOCKS, 256, 0, stream>>>(Fn, rowsum, pairsim);
  finalize_k<<<NROWS / 256, 256, 0, stream>>>(rowsum, pairsim, out);
}

// Round 13
// 103.691 us; speedup vs baseline: 2.3991x; 1.0071x over previous
//
#include <hip/hip_runtime.h>

#define NROWS 8192
#define HALF_N 4096
#define DIM 512
#define INV_T 10.0f
#define NRB 64              // number of 128-row blocks
#define NBLOCKS 2080        // 64*65/2 upper-triangle block pairs

typedef __attribute__((ext_vector_type(4))) float f32x4;
typedef __attribute__((ext_vector_type(2))) long long2v;

// async 16B global -> LDS (DMA). LDS dest is wave-uniform base + lane*16.
__device__ __forceinline__ void async16(const void* g, void* l) {
  __builtin_amdgcn_global_load_lds(
      (const __attribute__((address_space(1))) unsigned int*)g,
      (__attribute__((address_space(3))) unsigned int*)l, 16, 0, 0);
}

// Kernel 1: L2-normalize rows of [f1;f2] -> fp8 e4m3, written TWICE:
//  Fb: row-major, k-permuted within each 64B group (unit u -> pos
//      2*(u&3)+(u>>2)) — the B/LDS copy (R8-proven geometry).
//  Fa: fragment-major — panel p = row>>4 is 8 KB laid out as
//      [chunk c=0..31][row&15][16B], where chunk c holds k-units {c&3, (c&3)+4}
//      of k-group c>>2 (same pairing as Fb). A-fragment loads in the GEMM
//      become coalesced global b128 (quarter-wave = 256 B contiguous).
__global__ __launch_bounds__(256) void norm_cast_k(
    const float* __restrict__ f1, const float* __restrict__ f2,
    unsigned char* __restrict__ Fa, unsigned char* __restrict__ Fb,
    float* __restrict__ rowsum, float* __restrict__ out) {
  int wave = threadIdx.x >> 6;
  int lane = threadIdx.x & 63;
  int row = blockIdx.x * 4 + wave;
  const float* src = (row < HALF_N) ? (f1 + (size_t)row * DIM)
                                    : (f2 + (size_t)(row - HALF_N) * DIM);
  const float4* p = reinterpret_cast<const float4*>(src + lane * 8);
  float4 v0 = p[0];
  float4 v1 = p[1];
  float ss = v0.x*v0.x + v0.y*v0.y + v0.z*v0.z + v0.w*v0.w
           + v1.x*v1.x + v1.y*v1.y + v1.z*v1.z + v1.w*v1.w;
  #pragma unroll
  for (int off = 1; off < 64; off <<= 1) ss += __shfl_xor(ss, off);
  float scale = 1.0f / fmaxf(sqrtf(ss), 1e-12f);
  int lo = __builtin_amdgcn_cvt_pk_fp8_f32(v0.x * scale, v0.y * scale, 0, false);
  lo = __builtin_amdgcn_cvt_pk_fp8_f32(v0.z * scale, v0.w * scale, lo, true);
  int hi = __builtin_amdgcn_cvt_pk_fp8_f32(v1.x * scale, v1.y * scale, 0, false);
  hi = __builtin_amdgcn_cvt_pk_fp8_f32(v1.z * scale, v1.w * scale, hi, true);
  int2 val = make_int2(lo, hi);
  int u = lane & 7;                     // k-unit within 64B group
  int g = lane >> 3;                    // k-group (0..7)
  // Fb: row-major k-permuted
  int pos = 2 * (u & 3) + (u >> 2);
  *reinterpret_cast<int2*>(Fb + (size_t)row * DIM + g * 64 + pos * 8) = val;
  // Fa: fragment-major
  int chunk = g * 4 + (u & 3);          // global 16B chunk index (0..31)
  int slot = u >> 2;                    // which 8B half of the chunk
  *reinterpret_cast<int2*>(Fa + (size_t)(row >> 4) * 8192 + chunk * 256 +
                           (row & 15) * 16 + slot * 8) = val;
  if (lane == 0) rowsum[row] = 0.0f;
  if (blockIdx.x == 0 && threadIdx.x == 0) out[0] = 0.0f;
}

// Kernel 2: symmetric upper-triangle sim GEMM (fp8 e4m3), fused exp row/col
// accumulation. 128x128 tiles, BK=64 (8 rounds). B staged via global_load_lds
// (8 x 1KB insts/round, R8-proven swizzle); A fragments loaded DIRECTLY from
// global (Fa fragment-major copy, coalesced b128, L2-resident) — decoupled
// from the LDS barrier so their latency overlaps the DMA drain.
__global__ __launch_bounds__(256, 3) void sym_gemm_k(
    const unsigned char* __restrict__ Fa, const unsigned char* __restrict__ Fb,
    float* __restrict__ rowsum, float* __restrict__ pairsim) {
  // XCD-contiguous remap: each XCD (bx%8) gets a contiguous 260-block range
  int bx = blockIdx.x;
  int gbx = (bx & 7) * (NBLOCKS / 8) + (bx >> 3);
  int rb = 0, rem = gbx;
  while (rem >= NRB - rb) { rem -= NRB - rb; ++rb; }
  const int cb = rb + rem;
  const int row0 = rb * 128, col0 = cb * 128;

  const int tid = threadIdx.x;
  const int wave = tid >> 6;
  const int lane = tid & 63;
  const int quad = lane >> 4;
  const int colid = lane & 15;
  const int wr0 = (wave >> 1) * 64;   // wave's row offset within tile
  const int wc0 = (wave & 1) * 64;    // wave's col offset within tile

  // B LDS tile: 128 rows x 64 k fp8 = 64 B/row, 4 x 16B chunks per row.
  // Physical chunk = logical ^ ((row>>1)&3) -> conflict-free b128 reads.
  __shared__ __align__(16) unsigned char Blds[128 * 64];
  __shared__ float redrow[128];
  __shared__ float redcol[128];

  if (tid < 128) { redrow[tid] = 0.0f; redcol[tid] = 0.0f; }

  // B staging: 8 x 1KB insts/round, wave w owns insts {w, w+4}.
  // Inst i covers rows [i*16, i*16+16): lane -> r = i*16 + (lane>>2),
  // phys chunk = lane&3, global logical chunk = (lane&3) ^ ((r>>1)&3).
  const unsigned char* srcB[2]; unsigned char* dstB[2];
  #pragma unroll
  for (int seg = 0; seg < 2; ++seg) {
    int inst = wave + seg * 4;
    int r = inst * 16 + (lane >> 2);
    int c = (lane & 3) ^ ((r >> 1) & 3);
    srcB[seg] = Fb + (size_t)(col0 + r) * DIM + c * 16;
    dstB[seg] = Blds + inst * 1024;   // 16 rows x 64 B per inst
  }

  // A global fragment pointers: tile t -> panel (row0+wr0+t*16)>>4;
  // round kc, quad q -> chunk kc*4+q; lane colid -> row-in-panel.
  // Quarter-wave reads 16 x 16B = 256 B contiguous (coalesced, L2-hit).
  const unsigned char* agp[4];
  #pragma unroll
  for (int t = 0; t < 4; ++t)
    agp[t] = Fa + (size_t)((row0 + wr0 + t * 16) >> 4) * 8192 +
             quad * 256 + colid * 16;

  // B fragment LDS addresses: logical chunk = quad; phys = quad ^ ((r>>1)&3).
  const unsigned char* bfp[4];
  #pragma unroll
  for (int t = 0; t < 4; ++t) {
    int rc = wc0 + t * 16 + colid;
    bfp[t] = Blds + rc * 64 + ((quad ^ ((rc >> 1) & 3)) << 4);
  }

  f32x4 acc[4][4];
  #pragma unroll
  for (int t = 0; t < 4; ++t)
    #pragma unroll
    for (int u = 0; u < 4; ++u) acc[t][u] = (f32x4){0.f, 0.f, 0.f, 0.f};

  for (int kc = 0; kc < 8; ++kc) {
    __syncthreads();                   // prior round's B reads done
    const size_t ko = (size_t)kc * 64; // B: 64 k-elems = 64 B per row
    #pragma unroll
    for (int seg = 0; seg < 2; ++seg)
      async16(srcB[seg] + ko, dstB[seg]);
    // A fragment loads (global, coalesced): issued here so their L2
    // latency overlaps the DMA drain below.
    long2v af[4];
    #pragma unroll
    for (int t = 0; t < 4; ++t)
      af[t] = *reinterpret_cast<const long2v*>(agp[t] + kc * 1024);
    __syncthreads();                   // drains DMA -> B tile visible

    long2v bf[4];
    #pragma unroll
    for (int u = 0; u < 4; ++u) bf[u] = *reinterpret_cast<const long2v*>(bfp[u]);
    #pragma unroll
    for (int s = 0; s < 2; ++s)
      #pragma unroll
      for (int t = 0; t < 4; ++t)
        #pragma unroll
        for (int u = 0; u < 4; ++u)
          acc[t][u] = __builtin_amdgcn_mfma_f32_16x16x32_fp8_fp8(
              af[t][s], bf[u][s], acc[t][u], 0, 0, 0);
  }

  // Epilogue. C/D layout: col = lane&15, row = quad*4 + reg (m89-verified,
  // dtype-independent on gfx950).
  float re[4][4];
  float ce[4];
  #pragma unroll
  for (int t = 0; t < 4; ++t)
    #pragma unroll
    for (int r = 0; r < 4; ++r) re[t][r] = 0.0f;
  #pragma unroll
  for (int u = 0; u < 4; ++u) ce[u] = 0.0f;

  #pragma unroll
  for (int t = 0; t < 4; ++t) {
    #pragma unroll
    for (int u = 0; u < 4; ++u) {
      f32x4 a = acc[t][u];
      const int gc = col0 + wc0 + u * 16 + colid;
      #pragma unroll
      for (int r = 0; r < 4; ++r) {
        int grow = row0 + wr0 + t * 16 + quad * 4 + r;
        float sim = a[r] * INV_T;
        float e = (gc > grow) ? __expf(sim) : 0.0f;  // strict upper triangle
        re[t][r] += e;
        ce[u] += e;
        if (gc == grow + HALF_N && grow < HALF_N) {
          pairsim[grow] = sim;         // unique writer per pair
          pairsim[gc] = sim;
        }
      }
    }
  }

  // Row sums: reduce across the 16 col-lanes, LDS-accumulate.
  #pragma unroll
  for (int t = 0; t < 4; ++t)
    #pragma unroll
    for (int r = 0; r < 4; ++r) {
      float v = re[t][r];
      v += __shfl_xor(v, 1); v += __shfl_xor(v, 2);
      v += __shfl_xor(v, 4); v += __shfl_xor(v, 8);
      if (colid == 0) atomicAdd(&redrow[wr0 + t * 16 + quad * 4 + r], v);
    }
  // Col sums: reduce across the 4 quads (this wave's 64 rows).
  #pragma unroll
  for (int u = 0; u < 4; ++u) {
    float v = ce[u];
    v += __shfl_xor(v, 16); v += __shfl_xor(v, 32);
    if (lane < 16) atomicAdd(&redcol[wc0 + u * 16 + colid], v);
  }
  __syncthreads();
  if (tid < 128) atomicAdd(&rowsum[row0 + tid], redrow[tid]);
  else           atomicAdd(&rowsum[col0 + tid - 128], redcol[tid - 128]);
}

// Kernel 3: loss partials. 32 blocks x 256 threads, one row each;
// per-wave reduce then one atomicAdd per wave into out (zeroed in kernel 1).
__global__ __launch_bounds__(256) void finalize_k(
    const float* __restrict__ rowsum, const float* __restrict__ pairsim,
    float* __restrict__ out) {
  int i = blockIdx.x * 256 + threadIdx.x;
  float local = logf(rowsum[i]) - pairsim[i];
  #pragma unroll
  for (int off = 1; off < 64; off <<= 1) local += __shfl_xor(local, off);
  if ((threadIdx.x & 63) == 0)
    atomicAdd(out, local * (1.0f / (float)NROWS));
}

extern "C" void kernel_launch(void* const* d_in, const int* in_sizes, int n_in,
                              void* d_out, int out_size, void* d_ws, size_t ws_size,
                              hipStream_t stream) {
  const float* f1 = (const float*)d_in[0];
  const float* f2 = (const float*)d_in[1];
  unsigned char* Fa = (unsigned char*)d_ws;                     // 4 MB fp8
  unsigned char* Fb = Fa + (size_t)NROWS * DIM;                 // 4 MB fp8
  float* rowsum = (float*)(Fb + (size_t)NROWS * DIM);
  float* pairsim = rowsum + NROWS;
  float* out = (float*)d_out;

  norm_cast_k<<<NROWS / 4, 256, 0, stream>>>(f1, f2, Fa, Fb, rowsum, out);
  sym_gemm_k<<<NBLOCKS, 256, 0, stream>>>(Fa, Fb, rowsum, pairsim);
  finalize_k<<<NROWS / 256, 256, 0, stream>>>(rowsum, pairsim, out);
}